// Round 8
// baseline (1733.235 us; speedup 1.0000x reference)
//
#include <hip/hip_runtime.h>
#include <math.h>

typedef float  fx4  __attribute__((ext_vector_type(4)));
typedef short  bfx8 __attribute__((ext_vector_type(8)));

// Bilinear weights exactly mirroring the reference resize_bilinear.
__device__ __forceinline__ void bl_w(int o, int O, int I, int& i0, int& i1, float& w) {
    float r = (float)((double)I / (double)O);
    float f = (o + 0.5f) * r - 0.5f;
    f = fminf(fmaxf(f, 0.0f), (float)(I - 1));
    int a = (int)floorf(f);
    i0 = a;
    i1 = min(a + 1, I - 1);
    w = f - (float)a;
}

__device__ __forceinline__ unsigned int bf16rne(float f) {
    unsigned int x = __builtin_bit_cast(unsigned int, f);
    return ((x + 0x7fffu + ((x >> 16) & 1u)) >> 16) & 0xffffu;
}

// Meta: per (b,lvl): [0]=mh [1]=mw ; [2+4n..]=t,l,ch,cw ; [2+4N+2s..]=fh,fw (s=1.0,0.9,1.1)
__global__ void k_meta(const int* __restrict__ tlbr, const int* __restrict__ p_imgh,
                       const int* __restrict__ p_imgw, int B, int N, int ms,
                       int* __restrict__ meta) {
    if (blockIdx.x != 0 || threadIdx.x != 0) return;
    const int HFs[2] = {128, 64};
    const double SC[2] = {0.9, 1.1};
    int img_h = *p_imgh, img_w = *p_imgw;
    for (int b = 0; b < B; ++b)
      for (int lvl = 0; lvl < 2; ++lvl) {
        int HF = HFs[lvl], WF = HFs[lvl];
        double sh = (double)HF / (double)img_h;
        double sw = (double)WF / (double)img_w;
        int* m = meta + (b*2 + lvl)*ms;
        int mh = 0, mw = 0;
        for (int n = 0; n < N; ++n) {
            const int* bx = tlbr + ((size_t)(b*N) + n)*4;
            int t  = max((int)floor((double)bx[0]*sh), 0);
            int l  = max((int)floor((double)bx[1]*sw), 0);
            int bb = min((int)ceil((double)bx[2]*sh) + 1, HF);
            int rr = min((int)ceil((double)bx[3]*sw) + 1, WF);
            int chh = bb - t, cww = rr - l;
            m[2+4*n+0] = t; m[2+4*n+1] = l; m[2+4*n+2] = chh; m[2+4*n+3] = cww;
            mh = max(mh, chh); mw = max(mw, cww);
        }
        m[0] = mh; m[1] = mw;
        int fo = 2 + 4*N;
        m[fo+0] = mh; m[fo+1] = mw;
        for (int s = 0; s < 2; ++s) {
            int hs  = (int)ceil((double)mh * SC[s]); if (hs  <= 1) hs  = mh;
            int wsv = (int)ceil((double)mw * SC[s]); if (wsv <= 1) wsv = mw;
            m[fo+2+2*s] = hs; m[fo+2+2*s+1] = wsv;
        }
      }
}

// Fused crop-resize + filter-resize, MFMA A-frag swizzled order.
// k-step s = (c, kxg, kyg): lane-group g holds kx = kxg*4+g, j-elems are
// ky = kyg*8+j. u32 pair idx = (((lb*KT + s)*4 + g)*16 + m)*4 + jj/2.
template<int C, int KH, int KW, int NKYG>
__global__ void k_filters(const float* __restrict__ feat_all, const int* __restrict__ meta,
                          unsigned short* __restrict__ Wswz, int b0, int chunkB,
                          int N, int lvl, int ms, int HF, int WF) {
    constexpr int KWG = KW/4;
    constexpr int KT  = C*KWG*NKYG;
    long long idx = (long long)blockIdx.x*256 + threadIdx.x;
    long long total = (long long)chunkB * KT * 256;   // u32 pairs
    if (idx >= total) return;
    int jj = ((int)(idx & 3)) * 2;
    int m  = (int)((idx >> 2) & 15);
    int g  = (int)((idx >> 6) & 3);
    long long rest = idx >> 8;
    int s  = (int)(rest % KT);
    int lb = (int)(rest / KT);
    int kyg = s % NKYG; int s2 = s / NKYG;
    int kxg = s2 % KWG;
    int c   = s2 / KWG;
    int kx  = kxg*4 + g;
    int ky  = kyg*8 + jj;
    unsigned int outv = 0;
    int sc = m / N, n = m - sc*N;
    if (sc < 3) {
        int b = b0 + lb;
        const int* mt = meta + (b*2 + lvl)*ms;
        int mh = mt[0], mw = mt[1];
        int t = mt[2+4*n], l = mt[3+4*n], chh = mt[4+4*n], cww = mt[5+4*n];
        int fo = 2 + 4*N;
        int fh = mt[fo + 2*sc], fw = mt[fo + 2*sc + 1];
        int offy = KH/2 - fh/2, offx = KW/2 - fw/2;
        int fx = kx - offx;
        if (fx >= 0 && fx < fw) {
            const float* src = feat_all + ((size_t)b*C + c)*HF*WF;
            int px0, px1; float wx;
            bl_w(fx, fw, mw, px0, px1, wx);
            int ax0, ax1; float awx; bl_w(px0, mw, cww, ax0, ax1, awx);
            int bx0, bx1; float bwx; bl_w(px1, mw, cww, bx0, bx1, bwx);
            #pragma unroll
            for (int q = 0; q < 2; ++q) {
                int fy = ky + q - offy;
                if (fy >= 0 && fy < fh) {
                    int py0, py1; float wy;
                    bl_w(fy, fh, mh, py0, py1, wy);
                    float pv[2][2];
                    #pragma unroll
                    for (int pi = 0; pi < 2; ++pi) {
                        int py = pi ? py1 : py0;
                        int cy0, cy1; float cwy;
                        bl_w(py, mh, chh, cy0, cy1, cwy);
                        const float* r0 = src + (size_t)(t + cy0)*WF + l;
                        const float* r1 = src + (size_t)(t + cy1)*WF + l;
                        pv[pi][0] = (r0[ax0]*(1.f-cwy) + r1[ax0]*cwy)*(1.f-awx)
                                  + (r0[ax1]*(1.f-cwy) + r1[ax1]*cwy)*awx;
                        pv[pi][1] = (r0[bx0]*(1.f-cwy) + r1[bx0]*cwy)*(1.f-bwx)
                                  + (r0[bx1]*(1.f-cwy) + r1[bx1]*cwy)*bwx;
                    }
                    float v = (pv[0][0]*(1.f-wy) + pv[1][0]*wy)*(1.f-wx)
                            + (pv[0][1]*(1.f-wy) + pv[1][1]*wy)*wx;
                    outv |= bf16rne(v) << (16*q);
                }
            }
        }
    }
    ((unsigned int*)Wswz)[idx] = outv;
}

// MFMA implicit-GEMM xcorr, split-K, NDY output rows/block, double-buffered
// with async-stage split sized to fit the 128-VGPR budget:
//   PF(c+1) issue -> MFMA on buf[X] -> WR into buf[X^1] -> ONE barrier.
// Column-major bf16 LDS, RSTR odd x 16B (conflict-free b128 R+W).
template<int C, int KS, int KH, int KW, int H, int W, int NKYG, int NDY,
         int RSTR, int NCOL, int P>
__global__ __launch_bounds__(256, 4) void k_mfconv(
        const float* __restrict__ feat_all, const unsigned short* __restrict__ Wswz,
        float* __restrict__ part, int b0, int Btot, int N, int nks) {
    constexpr int KWG   = KW/4;
    constexpr int CHSTR = NCOL*RSTR;          // u16 elems per buffer
    constexpr int NROWS = KH + (NDY-1)*8;     // staged rows per column
    constexpr int NRT   = NROWS/8;
    constexpr int NCT   = NCOL/4;
    constexpr int KT    = C*KWG*NKYG;
    constexpr int NFR   = NKYG + NDY - 1;     // B-frags per kxg
    __shared__ __align__(16) unsigned short smem[2*CHSTR];

    const int xb  = blockIdx.x;
    const int yb  = blockIdx.y;
    const int zz  = blockIdx.z;
    const int ksp = zz % nks;
    const int lb  = zz / nks;
    const int b   = b0 + lb;
    const int y0  = (yb >> 3)*(8*NDY) + (yb & 7);
    const int tid = threadIdx.x;
    const int lane = tid & 63;
    const int wv   = tid >> 6;
    const int g    = lane >> 4;
    const int lm   = lane & 15;

    fx4 acc[NDY];
    #pragma unroll
    for (int t = 0; t < NDY; ++t) acc[t] = (fx4){0.f, 0.f, 0.f, 0.f};

    const float* feat = feat_all + (size_t)b * C * H * W;
    const unsigned short* Wlane = Wswz + ((size_t)lb*KT)*512 + lane*8;
    const int bcol0 = (wv*16 + lm + g)*RSTR;   // B base (elems), +4*RSTR per kxg

    // this thread's staging tile (one 8-row x 4-col transpose tile)
    const bool sact = tid < NCT*NRT;
    const int rt = tid % NRT, ct = tid / NRT;
    const int col0 = ct*4, r0 = rt*8;
    const int sx0 = xb*64 + col0 - P;
    float4 pf[8];

    auto PF = [&](int c) {               // issue global loads -> pf (no use)
        if (!sact) return;
        const float* src = feat + (size_t)c*H*W;
        #pragma unroll
        for (int rr = 0; rr < 8; ++rr) {
            int y = y0 + r0 + rr - P;
            bool yok = (y >= 0) && (y < H);
            if (yok && sx0 >= 0 && sx0 + 3 < W) {
                pf[rr] = *reinterpret_cast<const float4*>(src + (size_t)y*W + sx0);
            } else {
                float t4[4];
                #pragma unroll
                for (int j = 0; j < 4; ++j) {
                    int x = sx0 + j;
                    t4[j] = (yok && x >= 0 && x < W) ? src[(size_t)y*W + x] : 0.f;
                }
                pf[rr] = make_float4(t4[0], t4[1], t4[2], t4[3]);
            }
        }
    };
    auto WR = [&](unsigned short* buf) {  // convert + transpose-write pf
        if (!sact) return;
        #pragma unroll
        for (int j = 0; j < 4; ++j) {
            uint4 w4;
            w4.x = bf16rne(((const float*)&pf[0])[j]) | (bf16rne(((const float*)&pf[1])[j]) << 16);
            w4.y = bf16rne(((const float*)&pf[2])[j]) | (bf16rne(((const float*)&pf[3])[j]) << 16);
            w4.z = bf16rne(((const float*)&pf[4])[j]) | (bf16rne(((const float*)&pf[5])[j]) << 16);
            w4.w = bf16rne(((const float*)&pf[6])[j]) | (bf16rne(((const float*)&pf[7])[j]) << 16);
            *reinterpret_cast<uint4*>(buf + (col0 + j)*RSTR + r0) = w4;
        }
    };

    // prologue: stage channel 0 into buf0
    PF(ksp*KS);
    WR(smem);
    __syncthreads();

    #pragma unroll 1
    for (int ph = 0; ph < KS; ++ph) {
        const int c = ksp*KS + ph;
        if (ph + 1 < KS) PF(c + 1);                    // async issue (in flight)
        const unsigned short* sb = smem + (ph & 1)*CHSTR;
        const unsigned short* Wc = Wlane + ((size_t)c*KWG*NKYG)*512;
        #pragma unroll 2
        for (int kxg = 0; kxg < KWG; ++kxg) {
            bfx8 af[NKYG];
            #pragma unroll
            for (int kyg = 0; kyg < NKYG; ++kyg)
                af[kyg] = *reinterpret_cast<const bfx8*>(Wc + (size_t)(kxg*NKYG + kyg)*512);
            const unsigned short* bp = sb + bcol0 + kxg*4*RSTR;
            bfx8 fr[NFR];
            #pragma unroll
            for (int rg = 0; rg < NFR; ++rg)
                fr[rg] = *reinterpret_cast<const bfx8*>(bp + rg*8);
            __builtin_amdgcn_s_setprio(1);
            #pragma unroll
            for (int dy = 0; dy < NDY; ++dy)
                #pragma unroll
                for (int kyg = 0; kyg < NKYG; ++kyg)
                    acc[dy] = __builtin_amdgcn_mfma_f32_16x16x32_bf16(
                        af[kyg], fr[kyg + dy], acc[dy], 0, 0, 0);
            __builtin_amdgcn_s_setprio(0);
        }
        // WR targets the buffer whose reads finished before the PREVIOUS
        // barrier -> only one barrier per phase needed (publish writes).
        if (ph + 1 < KS) WR(smem + ((ph + 1) & 1)*CHSTR);
        __syncthreads();
    }
    // ---- epilogue: D row = g*4+r = filter m (sc*N+n), col = lane&15 ----
    const int x = xb*64 + wv*16 + lm;
    #pragma unroll
    for (int dy = 0; dy < NDY; ++dy) {
        int y = y0 + dy*8;
        if (y >= H) continue;
        #pragma unroll
        for (int r = 0; r < 4; ++r) {
            int m  = g*4 + r;
            int sc = m / N;
            int n  = m - sc*N;
            if (sc < 3) {
                size_t oi = ((((size_t)ksp*Btot + b)*N + n)*3 + sc)*((size_t)H*W)
                          + (size_t)y*W + x;
                part[oi] = acc[dy][r];
            }
        }
    }
}

// Sum m3 split-K partials -> out planes 0..2.
__global__ void k_reduce3(const float* __restrict__ part, float* __restrict__ out,
                          int B, int N, int nks) {
    int idx = blockIdx.x*256 + threadIdx.x;
    int tot = B*N*3*128*128;
    if (idx >= tot) return;
    int px = idx & 16383;
    int r = idx >> 14;
    int sc = r % 3; r /= 3;
    int n = r % N; int b = r / N;
    size_t stride = (size_t)B*N*3*16384;
    const float* p = part + ((size_t)(b*N + n)*3 + sc)*16384 + px;
    float s = 0.f;
    for (int ks = 0; ks < nks; ++ks) s += p[(size_t)ks*stride];
    out[(((size_t)(b*N + n)*6 + sc) << 14) + px] = s;
}

// Sum m4 split-K partials + 64->128 bilinear upsample -> out planes 3..5.
__global__ void k_upsample_sum(const float* __restrict__ part, float* __restrict__ out,
                               int B, int N, int nks) {
    int idx = blockIdx.x*256 + threadIdx.x;
    int tot = B*N*3*128*128;
    if (idx >= tot) return;
    int x = idx & 127; int r = idx >> 7;
    int y = r & 127; r >>= 7;
    int sc = r % 3; r /= 3;
    int n = r % N; int b = r / N;
    int y0, y1, x0, x1; float wy, wx;
    bl_w(y, 128, 64, y0, y1, wy);
    bl_w(x, 128, 64, x0, x1, wx);
    size_t stride = (size_t)B*N*3*4096;
    const float* p = part + ((size_t)(b*N + n)*3 + sc)*4096;
    float f00 = 0.f, f10 = 0.f, f01 = 0.f, f11 = 0.f;
    for (int ks = 0; ks < nks; ++ks) {
        const float* q = p + (size_t)ks*stride;
        f00 += q[y0*64 + x0]; f10 += q[y1*64 + x0];
        f01 += q[y0*64 + x1]; f11 += q[y1*64 + x1];
    }
    out[((size_t)((b*N + n)*6 + 3 + sc)*128 + y)*128 + x] =
        (f00*(1.f-wy) + f10*wy)*(1.f-wx) + (f01*(1.f-wy) + f11*wy)*wx;
}

extern "C" void kernel_launch(void* const* d_in, const int* in_sizes, int n_in,
                              void* d_out, int out_size, void* d_ws, size_t ws_size,
                              hipStream_t stream) {
    const float* map3 = (const float*)d_in[0];
    const float* map4 = (const float*)d_in[1];
    const int*   tlbr = (const int*)d_in[2];
    const int*   p_imgh = (const int*)d_in[3];
    const int*   p_imgw = (const int*)d_in[4];
    float* out = (float*)d_out;

    const int C3 = 512, H3 = 128, C4 = 1024, H4 = 64;
    int B = in_sizes[0] / (C3 * H3 * H3);
    int N = in_sizes[2] / (B * 4);
    int ms = 2 + 4 * N + 6;
    const int NKS3 = 8, NKS4 = 32;

    // Workspace: meta (4KB) | part (split-K partials, shared m3/m4) | Wbuf
    char* wsp = (char*)d_ws;
    int* meta = (int*)wsp;
    size_t off = 4096;
    float* part = (float*)(wsp + off);
    size_t part_bytes = (size_t)NKS3 * B * N * 3 * H3 * H3 * 4;  // == m4's NKS4 partials
    off += part_bytes;
    unsigned short* Wbuf = (unsigned short*)(wsp + off);
    size_t wavail = (ws_size > off) ? (ws_size - off) : 0;
    size_t wpb = (size_t)9216 * 1024;   // KT3=512*6*3=9216 k-steps x 1KB
    int cb = (int)(wavail / wpb); if (cb > B) cb = B; if (cb < 1) cb = 1;

    k_meta<<<1, 1, 0, stream>>>(tlbr, p_imgh, p_imgw, B, N, ms, meta);

    { // ---- level 0 (m3): filters -> split-K dbuf conv -> reduce ----
        for (int b0 = 0; b0 < B; b0 += cb) {
            int cbn = (cb < B - b0) ? cb : (B - b0);
            long long pr = (long long)cbn * 9216 * 256;
            k_filters<512,24,24,3><<<(int)((pr + 255) / 256), 256, 0, stream>>>(
                map3, meta, Wbuf, b0, cbn, N, 0, ms, H3, H3);
            dim3 grid(2, 24, cbn * NKS3);
            k_mfconv<512,64,24,24,128,128,3,6,72,88,12><<<grid, 256, 0, stream>>>(
                map3, Wbuf, part, b0, B, N, NKS3);
        }
        int tot = B * N * 3 * H3 * H3;
        k_reduce3<<<(tot + 255) / 256, 256, 0, stream>>>(part, out, B, N, NKS3);
    }
    { // ---- level 1 (m4): filters -> split-K dbuf conv -> reduce+upsample ----
        for (int b0 = 0; b0 < B; b0 += cb) {
            int cbn = (cb < B - b0) ? cb : (B - b0);
            long long pr = (long long)cbn * 8192 * 256;
            k_filters<1024,16,16,2><<<(int)((pr + 255) / 256), 256, 0, stream>>>(
                map4, meta, Wbuf, b0, cbn, N, 1, ms, H4, H4);
            dim3 grid(1, 16, cbn * NKS4);
            k_mfconv<1024,32,16,16,64,64,2,4,40,80,8><<<grid, 256, 0, stream>>>(
                map4, Wbuf, part, b0, B, N, NKS4);
        }
        int tot = B * N * 3 * H3 * H3;
        k_upsample_sum<<<(tot + 255) / 256, 256, 0, stream>>>(part, out, B, N, NKS4);
    }
}

// Round 9
// 991.071 us; speedup vs baseline: 1.7489x; 1.7489x over previous
//
#include <hip/hip_runtime.h>
#include <math.h>

typedef float  fx4  __attribute__((ext_vector_type(4)));
typedef short  bfx8 __attribute__((ext_vector_type(8)));

// Bilinear weights exactly mirroring the reference resize_bilinear.
__device__ __forceinline__ void bl_w(int o, int O, int I, int& i0, int& i1, float& w) {
    float r = (float)((double)I / (double)O);
    float f = (o + 0.5f) * r - 0.5f;
    f = fminf(fmaxf(f, 0.0f), (float)(I - 1));
    int a = (int)floorf(f);
    i0 = a;
    i1 = min(a + 1, I - 1);
    w = f - (float)a;
}

__device__ __forceinline__ unsigned int bf16rne(float f) {
    unsigned int x = __builtin_bit_cast(unsigned int, f);
    return ((x + 0x7fffu + ((x >> 16) & 1u)) >> 16) & 0xffffu;
}

// HW packed convert: D = bf16(lo) | bf16(hi)<<16, RNE — 1 VALU op vs ~7.
__device__ __forceinline__ unsigned int pk_bf16(float lo, float hi) {
    unsigned int r;
    asm("v_cvt_pk_bf16_f32 %0, %1, %2" : "=v"(r) : "v"(lo), "v"(hi));
    return r;
}

// Meta: per (b,lvl): [0]=mh [1]=mw ; [2+4n..]=t,l,ch,cw ; [2+4N+2s..]=fh,fw (s=1.0,0.9,1.1)
__global__ void k_meta(const int* __restrict__ tlbr, const int* __restrict__ p_imgh,
                       const int* __restrict__ p_imgw, int B, int N, int ms,
                       int* __restrict__ meta) {
    if (blockIdx.x != 0 || threadIdx.x != 0) return;
    const int HFs[2] = {128, 64};
    const double SC[2] = {0.9, 1.1};
    int img_h = *p_imgh, img_w = *p_imgw;
    for (int b = 0; b < B; ++b)
      for (int lvl = 0; lvl < 2; ++lvl) {
        int HF = HFs[lvl], WF = HFs[lvl];
        double sh = (double)HF / (double)img_h;
        double sw = (double)WF / (double)img_w;
        int* m = meta + (b*2 + lvl)*ms;
        int mh = 0, mw = 0;
        for (int n = 0; n < N; ++n) {
            const int* bx = tlbr + ((size_t)(b*N) + n)*4;
            int t  = max((int)floor((double)bx[0]*sh), 0);
            int l  = max((int)floor((double)bx[1]*sw), 0);
            int bb = min((int)ceil((double)bx[2]*sh) + 1, HF);
            int rr = min((int)ceil((double)bx[3]*sw) + 1, WF);
            int chh = bb - t, cww = rr - l;
            m[2+4*n+0] = t; m[2+4*n+1] = l; m[2+4*n+2] = chh; m[2+4*n+3] = cww;
            mh = max(mh, chh); mw = max(mw, cww);
        }
        m[0] = mh; m[1] = mw;
        int fo = 2 + 4*N;
        m[fo+0] = mh; m[fo+1] = mw;
        for (int s = 0; s < 2; ++s) {
            int hs  = (int)ceil((double)mh * SC[s]); if (hs  <= 1) hs  = mh;
            int wsv = (int)ceil((double)mw * SC[s]); if (wsv <= 1) wsv = mw;
            m[fo+2+2*s] = hs; m[fo+2+2*s+1] = wsv;
        }
      }
}

// Fused crop-resize + filter-resize, MFMA A-frag swizzled order.
// k-step s = (c, kxg, kyg): lane-group g holds kx = kxg*4+g, j-elems are
// ky = kyg*8+j. u32 pair idx = (((lb*KT + s)*4 + g)*16 + m)*4 + jj/2.
template<int C, int KH, int KW, int NKYG>
__global__ void k_filters(const float* __restrict__ feat_all, const int* __restrict__ meta,
                          unsigned short* __restrict__ Wswz, int b0, int chunkB,
                          int N, int lvl, int ms, int HF, int WF) {
    constexpr int KWG = KW/4;
    constexpr int KT  = C*KWG*NKYG;
    long long idx = (long long)blockIdx.x*256 + threadIdx.x;
    long long total = (long long)chunkB * KT * 256;   // u32 pairs
    if (idx >= total) return;
    int jj = ((int)(idx & 3)) * 2;
    int m  = (int)((idx >> 2) & 15);
    int g  = (int)((idx >> 6) & 3);
    long long rest = idx >> 8;
    int s  = (int)(rest % KT);
    int lb = (int)(rest / KT);
    int kyg = s % NKYG; int s2 = s / NKYG;
    int kxg = s2 % KWG;
    int c   = s2 / KWG;
    int kx  = kxg*4 + g;
    int ky  = kyg*8 + jj;
    unsigned int outv = 0;
    int sc = m / N, n = m - sc*N;
    if (sc < 3) {
        int b = b0 + lb;
        const int* mt = meta + (b*2 + lvl)*ms;
        int mh = mt[0], mw = mt[1];
        int t = mt[2+4*n], l = mt[3+4*n], chh = mt[4+4*n], cww = mt[5+4*n];
        int fo = 2 + 4*N;
        int fh = mt[fo + 2*sc], fw = mt[fo + 2*sc + 1];
        int offy = KH/2 - fh/2, offx = KW/2 - fw/2;
        int fx = kx - offx;
        if (fx >= 0 && fx < fw) {
            const float* src = feat_all + ((size_t)b*C + c)*HF*WF;
            int px0, px1; float wx;
            bl_w(fx, fw, mw, px0, px1, wx);
            int ax0, ax1; float awx; bl_w(px0, mw, cww, ax0, ax1, awx);
            int bx0, bx1; float bwx; bl_w(px1, mw, cww, bx0, bx1, bwx);
            #pragma unroll
            for (int q = 0; q < 2; ++q) {
                int fy = ky + q - offy;
                if (fy >= 0 && fy < fh) {
                    int py0, py1; float wy;
                    bl_w(fy, fh, mh, py0, py1, wy);
                    float pv[2][2];
                    #pragma unroll
                    for (int pi = 0; pi < 2; ++pi) {
                        int py = pi ? py1 : py0;
                        int cy0, cy1; float cwy;
                        bl_w(py, mh, chh, cy0, cy1, cwy);
                        const float* r0 = src + (size_t)(t + cy0)*WF + l;
                        const float* r1 = src + (size_t)(t + cy1)*WF + l;
                        pv[pi][0] = (r0[ax0]*(1.f-cwy) + r1[ax0]*cwy)*(1.f-awx)
                                  + (r0[ax1]*(1.f-cwy) + r1[ax1]*cwy)*awx;
                        pv[pi][1] = (r0[bx0]*(1.f-cwy) + r1[bx0]*cwy)*(1.f-bwx)
                                  + (r0[bx1]*(1.f-cwy) + r1[bx1]*cwy)*bwx;
                    }
                    float v = (pv[0][0]*(1.f-wy) + pv[1][0]*wy)*(1.f-wx)
                            + (pv[0][1]*(1.f-wy) + pv[1][1]*wy)*wx;
                    outv |= bf16rne(v) << (16*q);
                }
            }
        }
    }
    ((unsigned int*)Wswz)[idx] = outv;
}

// MFMA implicit-GEMM xcorr, split-K, NDY=8 output rows/block (round-6
// structure: synchronous CC=2 staging, 2 barriers/chunk). Column-major bf16
// LDS, RSTR odd x 16B (conflict-free b128 R+W). Staging pack uses HW
// v_cvt_pk_bf16_f32 (1 op per u32). 5 blocks/CU via launch_bounds.
template<int C, int KS, int KH, int KW, int H, int W, int NKYG, int NDY,
         int CC, int RSTR, int NCOL, int P>
__global__ __launch_bounds__(256, 5) void k_mfconv(
        const float* __restrict__ feat_all, const unsigned short* __restrict__ Wswz,
        float* __restrict__ part, int b0, int Btot, int N, int nks) {
    constexpr int KWG   = KW/4;
    constexpr int CHSTR = NCOL*RSTR;          // u16 elems per channel
    constexpr int NROWS = KH + (NDY-1)*8;     // staged rows per column
    constexpr int NRT   = NROWS/8;
    constexpr int NCT   = NCOL/4;
    constexpr int KT    = C*KWG*NKYG;
    constexpr int NFR   = NKYG + NDY - 1;     // B-frags per kxg
    __shared__ __align__(16) unsigned short smem[CC*CHSTR];

    const int xb  = blockIdx.x;
    const int yb  = blockIdx.y;
    const int zz  = blockIdx.z;
    const int ksp = zz % nks;
    const int lb  = zz / nks;
    const int b   = b0 + lb;
    const int y0  = (yb >> 3)*(8*NDY) + (yb & 7);
    const int tid = threadIdx.x;
    const int lane = tid & 63;
    const int wv   = tid >> 6;
    const int g    = lane >> 4;
    const int lm   = lane & 15;

    fx4 acc[NDY];
    #pragma unroll
    for (int t = 0; t < NDY; ++t) acc[t] = (fx4){0.f, 0.f, 0.f, 0.f};

    const float* feat = feat_all + (size_t)b * C * H * W;
    const unsigned short* Wlane = Wswz + ((size_t)lb*KT)*512 + lane*8;
    const int bcol0 = (wv*16 + lm + g)*RSTR;   // B base (elems), +4*RSTR per kxg

    for (int cb_ = 0; cb_ < KS; cb_ += CC) {
        const int c0 = ksp*KS + cb_;
        // ---- stage CC channels: 8-row x 4-col transpose tiles, b128 writes
        for (int it = tid; it < CC*NCT*NRT; it += 256) {
            int rt = it % NRT; int t2 = it / NRT;
            int ct = t2 % NCT; int ch = t2 / NCT;
            const float* src = feat + (size_t)(c0 + ch)*H*W;
            int col0 = ct*4, r0 = rt*8;
            int x0 = xb*64 + col0 - P;
            float4 f[8];
            #pragma unroll
            for (int rr = 0; rr < 8; ++rr) {
                int y = y0 + r0 + rr - P;
                bool yok = (y >= 0) && (y < H);
                if (yok && x0 >= 0 && x0 + 3 < W) {
                    f[rr] = *reinterpret_cast<const float4*>(src + (size_t)y*W + x0);
                } else {
                    float t4[4];
                    #pragma unroll
                    for (int j = 0; j < 4; ++j) {
                        int x = x0 + j;
                        t4[j] = (yok && x >= 0 && x < W) ? src[(size_t)y*W + x] : 0.f;
                    }
                    f[rr] = make_float4(t4[0], t4[1], t4[2], t4[3]);
                }
            }
            #pragma unroll
            for (int j = 0; j < 4; ++j) {
                uint4 w4;
                w4.x = pk_bf16(((const float*)&f[0])[j], ((const float*)&f[1])[j]);
                w4.y = pk_bf16(((const float*)&f[2])[j], ((const float*)&f[3])[j]);
                w4.z = pk_bf16(((const float*)&f[4])[j], ((const float*)&f[5])[j]);
                w4.w = pk_bf16(((const float*)&f[6])[j], ((const float*)&f[7])[j]);
                *reinterpret_cast<uint4*>(smem + ch*CHSTR + (col0 + j)*RSTR + r0) = w4;
            }
        }
        __syncthreads();
        // ---- MFMA: per (ch,kxg): NKYG A-loads, NFR B-reads, NKYG*NDY MFMAs
        #pragma unroll 1
        for (int ch = 0; ch < CC; ++ch) {
            const unsigned short* Wc = Wlane + ((size_t)(c0 + ch)*KWG*NKYG)*512;
            const unsigned short* sb = smem + ch*CHSTR;
            #pragma unroll 2
            for (int kxg = 0; kxg < KWG; ++kxg) {
                bfx8 af[NKYG];
                #pragma unroll
                for (int kyg = 0; kyg < NKYG; ++kyg)
                    af[kyg] = *reinterpret_cast<const bfx8*>(Wc + (size_t)(kxg*NKYG + kyg)*512);
                const unsigned short* bp = sb + bcol0 + kxg*4*RSTR;
                bfx8 fr[NFR];
                #pragma unroll
                for (int rg = 0; rg < NFR; ++rg)
                    fr[rg] = *reinterpret_cast<const bfx8*>(bp + rg*8);
                __builtin_amdgcn_s_setprio(1);
                #pragma unroll
                for (int dy = 0; dy < NDY; ++dy)
                    #pragma unroll
                    for (int kyg = 0; kyg < NKYG; ++kyg)
                        acc[dy] = __builtin_amdgcn_mfma_f32_16x16x32_bf16(
                            af[kyg], fr[kyg + dy], acc[dy], 0, 0, 0);
                __builtin_amdgcn_s_setprio(0);
            }
        }
        __syncthreads();
    }
    // ---- epilogue: D row = g*4+r = filter m (sc*N+n), col = lane&15 ----
    const int x = xb*64 + wv*16 + lm;
    #pragma unroll
    for (int dy = 0; dy < NDY; ++dy) {
        int y = y0 + dy*8;
        if (y >= H) continue;
        #pragma unroll
        for (int r = 0; r < 4; ++r) {
            int m  = g*4 + r;
            int sc = m / N;
            int n  = m - sc*N;
            if (sc < 3) {
                size_t oi = ((((size_t)ksp*Btot + b)*N + n)*3 + sc)*((size_t)H*W)
                          + (size_t)y*W + x;
                part[oi] = acc[dy][r];
            }
        }
    }
}

// Sum m3 split-K partials -> out planes 0..2.
__global__ void k_reduce3(const float* __restrict__ part, float* __restrict__ out,
                          int B, int N, int nks) {
    int idx = blockIdx.x*256 + threadIdx.x;
    int tot = B*N*3*128*128;
    if (idx >= tot) return;
    int px = idx & 16383;
    int r = idx >> 14;
    int sc = r % 3; r /= 3;
    int n = r % N; int b = r / N;
    size_t stride = (size_t)B*N*3*16384;
    const float* p = part + ((size_t)(b*N + n)*3 + sc)*16384 + px;
    float s = 0.f;
    for (int ks = 0; ks < nks; ++ks) s += p[(size_t)ks*stride];
    out[(((size_t)(b*N + n)*6 + sc) << 14) + px] = s;
}

// Sum m4 split-K partials + 64->128 bilinear upsample -> out planes 3..5.
__global__ void k_upsample_sum(const float* __restrict__ part, float* __restrict__ out,
                               int B, int N, int nks) {
    int idx = blockIdx.x*256 + threadIdx.x;
    int tot = B*N*3*128*128;
    if (idx >= tot) return;
    int x = idx & 127; int r = idx >> 7;
    int y = r & 127; r >>= 7;
    int sc = r % 3; r /= 3;
    int n = r % N; int b = r / N;
    int y0, y1, x0, x1; float wy, wx;
    bl_w(y, 128, 64, y0, y1, wy);
    bl_w(x, 128, 64, x0, x1, wx);
    size_t stride = (size_t)B*N*3*4096;
    const float* p = part + ((size_t)(b*N + n)*3 + sc)*4096;
    float f00 = 0.f, f10 = 0.f, f01 = 0.f, f11 = 0.f;
    for (int ks = 0; ks < nks; ++ks) {
        const float* q = p + (size_t)ks*stride;
        f00 += q[y0*64 + x0]; f10 += q[y1*64 + x0];
        f01 += q[y0*64 + x1]; f11 += q[y1*64 + x1];
    }
    out[((size_t)((b*N + n)*6 + 3 + sc)*128 + y)*128 + x] =
        (f00*(1.f-wy) + f10*wy)*(1.f-wx) + (f01*(1.f-wy) + f11*wy)*wx;
}

extern "C" void kernel_launch(void* const* d_in, const int* in_sizes, int n_in,
                              void* d_out, int out_size, void* d_ws, size_t ws_size,
                              hipStream_t stream) {
    const float* map3 = (const float*)d_in[0];
    const float* map4 = (const float*)d_in[1];
    const int*   tlbr = (const int*)d_in[2];
    const int*   p_imgh = (const int*)d_in[3];
    const int*   p_imgw = (const int*)d_in[4];
    float* out = (float*)d_out;

    const int C3 = 512, H3 = 128, C4 = 1024, H4 = 64;
    int B = in_sizes[0] / (C3 * H3 * H3);
    int N = in_sizes[2] / (B * 4);
    int ms = 2 + 4 * N + 6;
    const int NKS3 = 16, NKS4 = 64;   // 2048-block grids -> 5 blocks/CU resident

    // Workspace: meta (4KB) | part (split-K partials, shared m3/m4) | Wbuf
    char* wsp = (char*)d_ws;
    int* meta = (int*)wsp;
    size_t off = 4096;
    float* part = (float*)(wsp + off);
    size_t part_bytes = (size_t)NKS3 * B * N * 3 * H3 * H3 * 4;  // == m4's NKS4 partials
    off += part_bytes;
    unsigned short* Wbuf = (unsigned short*)(wsp + off);
    size_t wavail = (ws_size > off) ? (ws_size - off) : 0;
    size_t wpb = (size_t)9216 * 1024;   // KT3=512*6*3=9216 k-steps x 1KB
    int cb = (int)(wavail / wpb); if (cb > B) cb = B; if (cb < 1) cb = 1;

    k_meta<<<1, 1, 0, stream>>>(tlbr, p_imgh, p_imgw, B, N, ms, meta);

    { // ---- level 0 (m3): filters -> split-K conv -> reduce ----
        for (int b0 = 0; b0 < B; b0 += cb) {
            int cbn = (cb < B - b0) ? cb : (B - b0);
            long long pr = (long long)cbn * 9216 * 256;
            k_filters<512,24,24,3><<<(int)((pr + 255) / 256), 256, 0, stream>>>(
                map3, meta, Wbuf, b0, cbn, N, 0, ms, H3, H3);
            dim3 grid(2, 16, cbn * NKS3);
            k_mfconv<512,32,24,24,128,128,3,8,2,88,88,12><<<grid, 256, 0, stream>>>(
                map3, Wbuf, part, b0, B, N, NKS3);
        }
        int tot = B * N * 3 * H3 * H3;
        k_reduce3<<<(tot + 255) / 256, 256, 0, stream>>>(part, out, B, N, NKS3);
    }
    { // ---- level 1 (m4): filters -> split-K conv -> reduce+upsample ----
        for (int b0 = 0; b0 < B; b0 += cb) {
            int cbn = (cb < B - b0) ? cb : (B - b0);
            long long pr = (long long)cbn * 8192 * 256;
            k_filters<1024,16,16,2><<<(int)((pr + 255) / 256), 256, 0, stream>>>(
                map4, meta, Wbuf, b0, cbn, N, 1, ms, H4, H4);
            dim3 grid(1, 8, cbn * NKS4);
            k_mfconv<1024,16,16,16,64,64,2,8,2,72,80,8><<<grid, 256, 0, stream>>>(
                map4, Wbuf, part, b0, B, N, NKS4);
        }
        int tot = B * N * 3 * H3 * H3;
        k_upsample_sum<<<(tot + 255) / 256, 256, 0, stream>>>(part, out, B, N, NKS4);
    }
}